// Round 1
// baseline (2620.418 us; speedup 1.0000x reference)
//
#include <hip/hip_runtime.h>

#define BB 8
#define NN 4096
#define DD 64
#define SS 1024
#define KK 32
#define R2 0.04f

// ---------------- FPS: one block per batch, sequential 1024 steps ----------------
__global__ __launch_bounds__(1024) void fps_kernel(const float* __restrict__ xyz,
                                                   int* __restrict__ fps_idx) {
    __shared__ float sx[NN], sy[NN], sz[NN];
    __shared__ float sdist[NN];
    __shared__ float red_val[16];
    __shared__ int   red_idx[16];
    __shared__ int   s_far;

    const int b   = blockIdx.x;
    const int tid = threadIdx.x;
    const float* xb = xyz + (size_t)b * NN * 3;

    for (int i = tid; i < NN; i += 1024) {
        sx[i] = xb[i * 3 + 0];
        sy[i] = xb[i * 3 + 1];
        sz[i] = xb[i * 3 + 2];
        sdist[i] = 1e10f;
    }
    __syncthreads();

    int far = 0;
    for (int t = 0; t < SS; ++t) {
        if (tid == 0) fps_idx[b * SS + t] = far;   // scan emits pre-update carry
        const float cx = sx[far], cy = sy[far], cz = sz[far];

        float bestv = -1.0f;
        int   besti = 0x7fffffff;
        for (int i = tid; i < NN; i += 1024) {
            // exact ref order: ((dx^2 + dy^2) + dz^2), no FMA contraction
            float dx = __fsub_rn(sx[i], cx);
            float dy = __fsub_rn(sy[i], cy);
            float dz = __fsub_rn(sz[i], cz);
            float d  = __fadd_rn(__fadd_rn(__fmul_rn(dx, dx), __fmul_rn(dy, dy)),
                                 __fmul_rn(dz, dz));
            float nd = fminf(sdist[i], d);
            sdist[i] = nd;
            if (nd > bestv) { bestv = nd; besti = i; }   // strict > : first occurrence
        }
        // wave (64-lane) argmax reduce, tie -> smaller index
        for (int off = 32; off > 0; off >>= 1) {
            float ov = __shfl_down(bestv, off);
            int   oi = __shfl_down(besti, off);
            if (ov > bestv || (ov == bestv && oi < besti)) { bestv = ov; besti = oi; }
        }
        const int wave = tid >> 6;
        if ((tid & 63) == 0) { red_val[wave] = bestv; red_idx[wave] = besti; }
        __syncthreads();
        if (tid == 0) {
            float bv = red_val[0];
            int   bi = red_idx[0];
            for (int w = 1; w < 16; ++w) {
                if (red_val[w] > bv || (red_val[w] == bv && red_idx[w] < bi)) {
                    bv = red_val[w]; bi = red_idx[w];
                }
            }
            s_far = bi;
        }
        __syncthreads();
        far = s_far;
    }
}

// ---------------- Ball query: one wave per (b,s) ----------------
__global__ __launch_bounds__(256) void ball_kernel(const float* __restrict__ xyz,
                                                   const int* __restrict__ fps_idx,
                                                   int* __restrict__ ball_idx) {
    __shared__ int buf[4][KK];
    const int wave = threadIdx.x >> 6;
    const int lane = threadIdx.x & 63;
    const int gw   = blockIdx.x * 4 + wave;      // gw = b*SS + s
    const int b    = gw / SS;
    const float* xb = xyz + (size_t)b * NN * 3;

    const int   qi = fps_idx[gw];
    const float qx = xb[qi * 3 + 0], qy = xb[qi * 3 + 1], qz = xb[qi * 3 + 2];
    const float qn = __fadd_rn(__fadd_rn(__fmul_rn(qx, qx), __fmul_rn(qy, qy)),
                               __fmul_rn(qz, qz));

    int total = 0;
    for (int base = 0; base < NN && total < KK; base += 64) {
        const int n  = base + lane;
        const float px = xb[n * 3 + 0], py = xb[n * 3 + 1], pz = xb[n * 3 + 2];
        const float pn = __fadd_rn(__fadd_rn(__fmul_rn(px, px), __fmul_rn(py, py)),
                                   __fmul_rn(pz, pz));
        const float dt = __fadd_rn(__fadd_rn(__fmul_rn(qx, px), __fmul_rn(qy, py)),
                                   __fmul_rn(qz, pz));
        // exact ref order: d = (-2*dot) + |q|^2 + |p|^2
        const float d = __fadd_rn(__fadd_rn(__fmul_rn(-2.0f, dt), qn), pn);
        const bool hit = !(d > R2);               // include iff d <= r^2
        const unsigned long long mask = __ballot(hit);
        const int before = __popcll(mask & ((1ull << lane) - 1ull));
        const int pos = total + before;
        if (hit && pos < KK) buf[wave][pos] = n;
        total += (int)__popcll(mask);
    }
    __syncthreads();   // all 4 waves exit loop eventually; makes LDS writes visible
    if (lane < KK) {
        const int v = (lane < total) ? buf[wave][lane] : buf[wave][0];
        ball_idx[gw * KK + lane] = v;
    }
}

// ---------------- Output assembly: one block per (b,s) ----------------
__global__ __launch_bounds__(256) void write_kernel(const float* __restrict__ xyz,
                                                    const float* __restrict__ points,
                                                    const int* __restrict__ fps_idx,
                                                    const int* __restrict__ ball_idx,
                                                    float* __restrict__ out) {
    const int bs = blockIdx.x;                   // 0..B*SS-1
    const int b  = bs / SS;
    __shared__ int   sidx[KK];
    __shared__ float sanchor[DD];
    __shared__ int   sq;
    const int tid = threadIdx.x;

    if (tid < KK) sidx[tid] = ball_idx[bs * KK + tid];
    if (tid == 0) sq = fps_idx[bs];
    __syncthreads();
    const int qi = sq;
    const float* xb = xyz + (size_t)b * NN * 3;
    const float* pb = points + (size_t)b * NN * DD;
    if (tid < DD) sanchor[tid] = pb[qi * DD + tid];
    if (tid < 3)  out[(size_t)bs * 3 + tid] = xb[qi * 3 + tid];
    __syncthreads();

    float* outp = out + (size_t)BB * SS * 3 + (size_t)bs * KK * 131;
    for (int c = tid; c < KK * 131; c += 256) {
        const int k = c / 131;
        const int j = c - k * 131;
        const int idx = sidx[k];
        float v;
        if (j < DD)          v = pb[idx * DD + j];
        else if (j < DD + 3) v = xb[idx * 3 + (j - DD)];
        else                 v = sanchor[j - DD - 3];
        outp[c] = v;
    }
}

extern "C" void kernel_launch(void* const* d_in, const int* in_sizes, int n_in,
                              void* d_out, int out_size, void* d_ws, size_t ws_size,
                              hipStream_t stream) {
    const float* xyz    = (const float*)d_in[0];   // [B,N,3]
    const float* points = (const float*)d_in[1];   // [B,N,D]
    float* out = (float*)d_out;

    int* fps  = (int*)d_ws;                        // [B*S]
    int* ball = fps + BB * SS;                     // [B*S*K]

    fps_kernel<<<BB, 1024, 0, stream>>>(xyz, fps);
    ball_kernel<<<(BB * SS) / 4, 256, 0, stream>>>(xyz, fps, ball);
    write_kernel<<<BB * SS, 256, 0, stream>>>(xyz, points, fps, ball, out);
}

// Round 2
// 908.450 us; speedup vs baseline: 2.8845x; 2.8845x over previous
//
#include <hip/hip_runtime.h>

#define BB 8
#define NN 4096
#define DD 64
#define SS 1024
#define KK 32
#define R2 0.04f

// ---------------- FPS: one block (256 thr) per batch, state in registers ----------------
// 16 points per lane in VGPRs; packed u64 argmax (val_bits<<32 | ~idx) so a single
// unsigned max gives max-distance with smallest-index tie-break (ref argmax semantics).
// One __syncthreads per step; red[] parity-double-buffered to kill the WAR hazard.
__global__ __launch_bounds__(256) void fps_kernel(const float* __restrict__ xyz,
                                                  int* __restrict__ fps_idx) {
    __shared__ float sx[NN], sy[NN], sz[NN];
    __shared__ unsigned long long red[2][4];

    const int b   = blockIdx.x;
    const int tid = threadIdx.x;
    const float* xb = xyz + (size_t)b * NN * 3;

    float px[16], py[16], pz[16], dist[16];
#pragma unroll
    for (int j = 0; j < 16; ++j) {
        const int i = tid + 256 * j;
        const float x = xb[i * 3 + 0];
        const float y = xb[i * 3 + 1];
        const float z = xb[i * 3 + 2];
        px[j] = x; py[j] = y; pz[j] = z;
        sx[i] = x; sy[i] = y; sz[i] = z;
        dist[j] = 1e10f;
    }
    __syncthreads();

    int far = 0;
    for (int t = 0; t < SS; ++t) {
        if (tid == 0) fps_idx[b * SS + t] = far;   // scan emits pre-update carry
        const float cx = sx[far], cy = sy[far], cz = sz[far];  // LDS broadcast

        float bestv = -1.0f;
        int   bestj = 0;
#pragma unroll
        for (int j = 0; j < 16; ++j) {
            // exact ref order: ((dx^2 + dy^2) + dz^2), no FMA contraction
            const float dx = __fsub_rn(px[j], cx);
            const float dy = __fsub_rn(py[j], cy);
            const float dz = __fsub_rn(pz[j], cz);
            const float d  = __fadd_rn(__fadd_rn(__fmul_rn(dx, dx), __fmul_rn(dy, dy)),
                                       __fmul_rn(dz, dz));
            const float nd = fminf(dist[j], d);    // fmin is exact; order-independent
            dist[j] = nd;
            if (nd > bestv) { bestv = nd; bestj = j; }  // strict >: first (smallest i)
        }
        const int besti = tid + 256 * bestj;       // ascending j == ascending global idx
        unsigned long long p =
            ((unsigned long long)__float_as_uint(bestv) << 32) | (unsigned)(~besti);

#pragma unroll
        for (int off = 32; off > 0; off >>= 1) {   // wave64 u64-max reduce
            const unsigned long long o = __shfl_down(p, off);
            if (o > p) p = o;
        }
        const int wave = tid >> 6;
        if ((tid & 63) == 0) red[t & 1][wave] = p;
        __syncthreads();                           // the only barrier in the step
        unsigned long long m = red[t & 1][0];
#pragma unroll
        for (int w = 1; w < 4; ++w) {
            const unsigned long long o = red[t & 1][w];
            if (o > m) m = o;
        }
        far = (int)(~(unsigned)m);                 // recover winning index
    }
}

// ---------------- Ball query: one wave per (b,s) ----------------
__global__ __launch_bounds__(256) void ball_kernel(const float* __restrict__ xyz,
                                                   const int* __restrict__ fps_idx,
                                                   int* __restrict__ ball_idx) {
    __shared__ int buf[4][KK];
    const int wave = threadIdx.x >> 6;
    const int lane = threadIdx.x & 63;
    const int gw   = blockIdx.x * 4 + wave;      // gw = b*SS + s
    const int b    = gw / SS;
    const float* xb = xyz + (size_t)b * NN * 3;

    const int   qi = fps_idx[gw];
    const float qx = xb[qi * 3 + 0], qy = xb[qi * 3 + 1], qz = xb[qi * 3 + 2];
    const float qn = __fadd_rn(__fadd_rn(__fmul_rn(qx, qx), __fmul_rn(qy, qy)),
                               __fmul_rn(qz, qz));

    int total = 0;
    for (int base = 0; base < NN && total < KK; base += 64) {
        const int n  = base + lane;
        const float px = xb[n * 3 + 0], py = xb[n * 3 + 1], pz = xb[n * 3 + 2];
        const float pn = __fadd_rn(__fadd_rn(__fmul_rn(px, px), __fmul_rn(py, py)),
                                   __fmul_rn(pz, pz));
        const float dt = __fadd_rn(__fadd_rn(__fmul_rn(qx, px), __fmul_rn(qy, py)),
                                   __fmul_rn(qz, pz));
        // exact ref order: d = (-2*dot) + |q|^2 + |p|^2
        const float d = __fadd_rn(__fadd_rn(__fmul_rn(-2.0f, dt), qn), pn);
        const bool hit = !(d > R2);               // include iff d <= r^2
        const unsigned long long mask = __ballot(hit);
        const int before = __popcll(mask & ((1ull << lane) - 1ull));
        const int pos = total + before;
        if (hit && pos < KK) buf[wave][pos] = n;
        total += (int)__popcll(mask);
    }
    __syncthreads();   // all 4 waves exit loop eventually; makes LDS writes visible
    if (lane < KK) {
        const int v = (lane < total) ? buf[wave][lane] : buf[wave][0];
        ball_idx[gw * KK + lane] = v;
    }
}

// ---------------- Output assembly: one block per (b,s) ----------------
__global__ __launch_bounds__(256) void write_kernel(const float* __restrict__ xyz,
                                                    const float* __restrict__ points,
                                                    const int* __restrict__ fps_idx,
                                                    const int* __restrict__ ball_idx,
                                                    float* __restrict__ out) {
    const int bs = blockIdx.x;                   // 0..B*SS-1
    const int b  = bs / SS;
    __shared__ int   sidx[KK];
    __shared__ float sanchor[DD];
    __shared__ int   sq;
    const int tid = threadIdx.x;

    if (tid < KK) sidx[tid] = ball_idx[bs * KK + tid];
    if (tid == 0) sq = fps_idx[bs];
    __syncthreads();
    const int qi = sq;
    const float* xb = xyz + (size_t)b * NN * 3;
    const float* pb = points + (size_t)b * NN * DD;
    if (tid < DD) sanchor[tid] = pb[qi * DD + tid];
    if (tid < 3)  out[(size_t)bs * 3 + tid] = xb[qi * 3 + tid];
    __syncthreads();

    float* outp = out + (size_t)BB * SS * 3 + (size_t)bs * KK * 131;
    for (int c = tid; c < KK * 131; c += 256) {
        const int k = c / 131;
        const int j = c - k * 131;
        const int idx = sidx[k];
        float v;
        if (j < DD)          v = pb[idx * DD + j];
        else if (j < DD + 3) v = xb[idx * 3 + (j - DD)];
        else                 v = sanchor[j - DD - 3];
        outp[c] = v;
    }
}

extern "C" void kernel_launch(void* const* d_in, const int* in_sizes, int n_in,
                              void* d_out, int out_size, void* d_ws, size_t ws_size,
                              hipStream_t stream) {
    const float* xyz    = (const float*)d_in[0];   // [B,N,3]
    const float* points = (const float*)d_in[1];   // [B,N,D]
    float* out = (float*)d_out;

    int* fps  = (int*)d_ws;                        // [B*S]
    int* ball = fps + BB * SS;                     // [B*S*K]

    fps_kernel<<<BB, 256, 0, stream>>>(xyz, fps);
    ball_kernel<<<(BB * SS) / 4, 256, 0, stream>>>(xyz, fps, ball);
    write_kernel<<<BB * SS, 256, 0, stream>>>(xyz, points, fps, ball, out);
}

// Round 3
// 828.042 us; speedup vs baseline: 3.1646x; 1.0971x over previous
//
#include <hip/hip_runtime.h>

#define BB 8
#define NN 4096
#define DD 64
#define SS 1024
#define KK 32
#define R2 0.04f

// u64 packed max step via DPP on both 32-bit halves. old = self, so masked/invalid
// lanes contribute their own value (identity under max). Canonical gfx9 sequence:
// row_shr:1,2,4,8 then row_bcast:15, row_bcast:31 -> lane 63 holds the wave max.
#define DPP_STAGE(p, CTRL)                                                            \
    {                                                                                 \
        unsigned _lo = (unsigned)(p), _hi = (unsigned)((p) >> 32);                    \
        unsigned _olo = (unsigned)__builtin_amdgcn_update_dpp((int)_lo, (int)_lo,     \
                                                              CTRL, 0xf, 0xf, false); \
        unsigned _ohi = (unsigned)__builtin_amdgcn_update_dpp((int)_hi, (int)_hi,     \
                                                              CTRL, 0xf, 0xf, false); \
        unsigned long long _o = ((unsigned long long)_ohi << 32) | _olo;              \
        if (_o > (p)) (p) = _o;                                                       \
    }

// ---------------- FPS: one block (512 thr) per batch, state in registers ----------------
// 8 points per lane (strided i = tid + 512*j); packed u64 (val_bits<<32 | ~idx) gives
// max-value with smallest-global-index tie-break under plain unsigned max (vals >= 0).
// Wave reduce via DPP (VALU latency, no ds_bpermute); cross-wave via 8-entry LDS scan.
__global__ __launch_bounds__(512) void fps_kernel(const float* __restrict__ xyz,
                                                  int* __restrict__ fps_idx) {
    __shared__ float sx[NN], sy[NN], sz[NN];
    __shared__ unsigned long long red[2][8];

    const int b   = blockIdx.x;
    const int tid = threadIdx.x;
    const float* xb = xyz + (size_t)b * NN * 3;

    float px[8], py[8], pz[8], dist[8];
#pragma unroll
    for (int j = 0; j < 8; ++j) {
        const int i = tid + 512 * j;
        const float x = xb[i * 3 + 0];
        const float y = xb[i * 3 + 1];
        const float z = xb[i * 3 + 2];
        px[j] = x; py[j] = y; pz[j] = z;
        sx[i] = x; sy[i] = y; sz[i] = z;
        dist[j] = 1e10f;
    }
    __syncthreads();

    int far = 0;
    for (int t = 0; t < SS; ++t) {
        if (tid == 0) fps_idx[b * SS + t] = far;   // scan emits pre-update carry
        const float cx = sx[far], cy = sy[far], cz = sz[far];  // broadcast reads

        float bestv = -1.0f;
        int   bestj = 0;
#pragma unroll
        for (int j = 0; j < 8; ++j) {
            // exact ref order: ((dx^2 + dy^2) + dz^2), no FMA contraction
            const float dx = __fsub_rn(px[j], cx);
            const float dy = __fsub_rn(py[j], cy);
            const float dz = __fsub_rn(pz[j], cz);
            const float d  = __fadd_rn(__fadd_rn(__fmul_rn(dx, dx), __fmul_rn(dy, dy)),
                                       __fmul_rn(dz, dz));
            const float nd = fminf(dist[j], d);    // fmin exact; order-independent
            dist[j] = nd;
            if (nd > bestv) { bestv = nd; bestj = j; }  // strict >: smallest j
        }
        const int besti = tid + 512 * bestj;       // ascending j == ascending global idx
        unsigned long long p =
            ((unsigned long long)__float_as_uint(bestv) << 32) | (unsigned)(~besti);

        DPP_STAGE(p, 0x111);   // row_shr:1
        DPP_STAGE(p, 0x112);   // row_shr:2
        DPP_STAGE(p, 0x114);   // row_shr:4
        DPP_STAGE(p, 0x118);   // row_shr:8
        DPP_STAGE(p, 0x142);   // row_bcast:15
        DPP_STAGE(p, 0x143);   // row_bcast:31  -> lane 63 has wave max

        const int par = t & 1;                     // parity double-buffer (WAR-safe)
        if ((tid & 63) == 63) red[par][tid >> 6] = p;
        __syncthreads();                           // the only barrier in the step
        unsigned long long m = red[par][0];
#pragma unroll
        for (int w = 1; w < 8; ++w) {
            const unsigned long long o = red[par][w];
            if (o > m) m = o;
        }
        far = (int)(~(unsigned)m);                 // recover winning index
    }
}

// ---------------- Ball query: one wave per (b,s) ----------------
__global__ __launch_bounds__(256) void ball_kernel(const float* __restrict__ xyz,
                                                   const int* __restrict__ fps_idx,
                                                   int* __restrict__ ball_idx) {
    __shared__ int buf[4][KK];
    const int wave = threadIdx.x >> 6;
    const int lane = threadIdx.x & 63;
    const int gw   = blockIdx.x * 4 + wave;      // gw = b*SS + s
    const int b    = gw / SS;
    const float* xb = xyz + (size_t)b * NN * 3;

    const int   qi = fps_idx[gw];
    const float qx = xb[qi * 3 + 0], qy = xb[qi * 3 + 1], qz = xb[qi * 3 + 2];
    const float qn = __fadd_rn(__fadd_rn(__fmul_rn(qx, qx), __fmul_rn(qy, qy)),
                               __fmul_rn(qz, qz));

    int total = 0;
    for (int base = 0; base < NN && total < KK; base += 64) {
        const int n  = base + lane;
        const float px = xb[n * 3 + 0], py = xb[n * 3 + 1], pz = xb[n * 3 + 2];
        const float pn = __fadd_rn(__fadd_rn(__fmul_rn(px, px), __fmul_rn(py, py)),
                                   __fmul_rn(pz, pz));
        const float dt = __fadd_rn(__fadd_rn(__fmul_rn(qx, px), __fmul_rn(qy, py)),
                                   __fmul_rn(qz, pz));
        // exact ref order: d = (-2*dot) + |q|^2 + |p|^2
        const float d = __fadd_rn(__fadd_rn(__fmul_rn(-2.0f, dt), qn), pn);
        const bool hit = !(d > R2);               // include iff d <= r^2
        const unsigned long long mask = __ballot(hit);
        const int before = __popcll(mask & ((1ull << lane) - 1ull));
        const int pos = total + before;
        if (hit && pos < KK) buf[wave][pos] = n;
        total += (int)__popcll(mask);
    }
    __syncthreads();   // all 4 waves exit loop eventually; makes LDS writes visible
    if (lane < KK) {
        const int v = (lane < total) ? buf[wave][lane] : buf[wave][0];
        ball_idx[gw * KK + lane] = v;
    }
}

// ---------------- Output assembly: one block per (b,s) ----------------
__global__ __launch_bounds__(256) void write_kernel(const float* __restrict__ xyz,
                                                    const float* __restrict__ points,
                                                    const int* __restrict__ fps_idx,
                                                    const int* __restrict__ ball_idx,
                                                    float* __restrict__ out) {
    const int bs = blockIdx.x;                   // 0..B*SS-1
    const int b  = bs / SS;
    __shared__ int   sidx[KK];
    __shared__ float sanchor[DD];
    __shared__ int   sq;
    const int tid = threadIdx.x;

    if (tid < KK) sidx[tid] = ball_idx[bs * KK + tid];
    if (tid == 0) sq = fps_idx[bs];
    __syncthreads();
    const int qi = sq;
    const float* xb = xyz + (size_t)b * NN * 3;
    const float* pb = points + (size_t)b * NN * DD;
    if (tid < DD) sanchor[tid] = pb[qi * DD + tid];
    if (tid < 3)  out[(size_t)bs * 3 + tid] = xb[qi * 3 + tid];
    __syncthreads();

    float* outp = out + (size_t)BB * SS * 3 + (size_t)bs * KK * 131;
    for (int c = tid; c < KK * 131; c += 256) {
        const int k = c / 131;
        const int j = c - k * 131;
        const int idx = sidx[k];
        float v;
        if (j < DD)          v = pb[idx * DD + j];
        else if (j < DD + 3) v = xb[idx * 3 + (j - DD)];
        else                 v = sanchor[j - DD - 3];
        outp[c] = v;
    }
}

extern "C" void kernel_launch(void* const* d_in, const int* in_sizes, int n_in,
                              void* d_out, int out_size, void* d_ws, size_t ws_size,
                              hipStream_t stream) {
    const float* xyz    = (const float*)d_in[0];   // [B,N,3]
    const float* points = (const float*)d_in[1];   // [B,N,D]
    float* out = (float*)d_out;

    int* fps  = (int*)d_ws;                        // [B*S]
    int* ball = fps + BB * SS;                     // [B*S*K]

    fps_kernel<<<BB, 512, 0, stream>>>(xyz, fps);
    ball_kernel<<<(BB * SS) / 4, 256, 0, stream>>>(xyz, fps, ball);
    write_kernel<<<BB * SS, 256, 0, stream>>>(xyz, points, fps, ball, out);
}

// Round 4
// 787.045 us; speedup vs baseline: 3.3294x; 1.0521x over previous
//
#include <hip/hip_runtime.h>

#define BB 8
#define NN 4096
#define DD 64
#define SS 1024
#define KK 32
#define R2 0.04f

typedef float f32x2 __attribute__((ext_vector_type(2)));

// One DPP max stage: wv = max(wv, lanes-shifted wv). old = self -> invalid lanes
// contribute identity. GCNDPPCombine fuses mov_dpp + v_max_f32 into v_max_f32_dpp.
#define DPP_MAXF(wv, CTRL)                                                             \
    {                                                                                  \
        int _o = __builtin_amdgcn_update_dpp(__float_as_int(wv), __float_as_int(wv),   \
                                             CTRL, 0xf, 0xf, false);                   \
        (wv) = fmaxf((wv), __int_as_float(_o));                                        \
    }

// ---------------- FPS: one block (512 thr) per batch, state in registers ----------------
// Contiguous layout: lane owns points i = tid*8 + j (j=0..7) as float2 pairs so the
// distance update compiles to packed v_pk_{add,mul}_f32 (exact per-element RN; fp
// contract OFF so no FMA fusion). Argmax: per-lane max tree + smallest-j scan; wave
// max via 6 fused DPP f32-max; index recovered with ballot+ffs+readlane (smallest
// lane = smallest tid = smallest global index). Cross-wave via 8-entry packed-u64
// LDS scan: (val_bits<<32)|~idx so u64 max = max value, smallest index tie-break.
__global__ __launch_bounds__(512) void fps_kernel(const float* __restrict__ xyz,
                                                  int* __restrict__ fps_idx) {
#pragma clang fp contract(off)
    __shared__ float sx[NN], sy[NN], sz[NN];
    __shared__ unsigned long long red[2][8];

    const int b   = blockIdx.x;
    const int tid = threadIdx.x;
    const float* xb = xyz + (size_t)b * NN * 3;

    // ---- init: 96 contiguous bytes per lane (8 points x 3 floats) via 6x float4 ----
    const float4* xb4 = (const float4*)(xb + tid * 24);
    const float4 q0 = xb4[0], q1 = xb4[1], q2 = xb4[2];
    const float4 q3 = xb4[3], q4 = xb4[4], q5 = xb4[5];

    f32x2 px[4], py[4], pz[4], dist[4];
    px[0] = (f32x2){q0.x, q0.w}; py[0] = (f32x2){q0.y, q1.x}; pz[0] = (f32x2){q0.z, q1.y};
    px[1] = (f32x2){q1.z, q2.y}; py[1] = (f32x2){q1.w, q2.z}; pz[1] = (f32x2){q2.x, q2.w};
    px[2] = (f32x2){q3.x, q3.w}; py[2] = (f32x2){q3.y, q4.x}; pz[2] = (f32x2){q3.z, q4.y};
    px[3] = (f32x2){q4.z, q5.y}; py[3] = (f32x2){q4.w, q5.z}; pz[3] = (f32x2){q5.x, q5.w};
#pragma unroll
    for (int jj = 0; jj < 4; ++jj) {
        const int i0 = tid * 8 + 2 * jj;
        sx[i0] = px[jj].x; sx[i0 + 1] = px[jj].y;
        sy[i0] = py[jj].x; sy[i0 + 1] = py[jj].y;
        sz[i0] = pz[jj].x; sz[i0 + 1] = pz[jj].y;
        dist[jj] = (f32x2){1e10f, 1e10f};
    }
    __syncthreads();

    int far = 0;
    for (int t = 0; t < SS; ++t) {
        if (tid == 0) fps_idx[b * SS + t] = far;   // scan emits pre-update carry
        const float cx = sx[far], cy = sy[far], cz = sz[far];  // LDS broadcast reads
        const f32x2 cx2 = (f32x2){cx, cx}, cy2 = (f32x2){cy, cy}, cz2 = (f32x2){cz, cz};

        f32x2 nd[4];
#pragma unroll
        for (int jj = 0; jj < 4; ++jj) {
            // exact ref order: ((dx^2 + dy^2) + dz^2); contract(off) => no FMA
            const f32x2 dx = px[jj] - cx2;
            const f32x2 dy = py[jj] - cy2;
            const f32x2 dz = pz[jj] - cz2;
            const f32x2 d  = (dx * dx + dy * dy) + dz * dz;
            f32x2 m;
            m.x = fminf(dist[jj].x, d.x);          // fmin exact; order-independent
            m.y = fminf(dist[jj].y, d.y);
            dist[jj] = m;
            nd[jj] = m;
        }
        // per-lane max (tree; values are non-negative, no NaN)
        const float bestv = fmaxf(fmaxf(fmaxf(nd[0].x, nd[0].y), fmaxf(nd[1].x, nd[1].y)),
                                  fmaxf(fmaxf(nd[2].x, nd[2].y), fmaxf(nd[3].x, nd[3].y)));
        // smallest j achieving it (descending scan => first match wins)
        int localj = 0;
#pragma unroll
        for (int j = 7; j >= 0; --j) {
            const float v = (j & 1) ? nd[j >> 1].y : nd[j >> 1].x;
            if (v == bestv) localj = j;
        }

        // wave max of bestv via fused DPP f32 max; lane 63 ends with the wave max
        float wv = bestv;
        DPP_MAXF(wv, 0x111);   // row_shr:1
        DPP_MAXF(wv, 0x112);   // row_shr:2
        DPP_MAXF(wv, 0x114);   // row_shr:4
        DPP_MAXF(wv, 0x118);   // row_shr:8
        DPP_MAXF(wv, 0x142);   // row_bcast:15
        DPP_MAXF(wv, 0x143);   // row_bcast:31
        const float maxw = __int_as_float(__builtin_amdgcn_readlane(__float_as_int(wv), 63));

        // first lane (== smallest tid) holding the max; fetch its candidate index
        const unsigned long long hits = __ballot(bestv == maxw);
        const int L = __ffsll((unsigned long long)hits) - 1;
        const int candv = tid * 8 + localj;        // == global point index i
        const int cand  = __builtin_amdgcn_readlane(candv, L);

        const unsigned long long p =
            ((unsigned long long)__float_as_uint(maxw) << 32) | (unsigned)(~cand);
        const int par = t & 1;                     // parity double-buffer (WAR-safe)
        if ((tid & 63) == 0) red[par][tid >> 6] = p;
        __syncthreads();                           // the only barrier in the step
        unsigned long long m = red[par][0];
#pragma unroll
        for (int w = 1; w < 8; ++w) {
            const unsigned long long o = red[par][w];
            if (o > m) m = o;
        }
        far = (int)(~(unsigned)m);                 // recover winning index
    }
}

// ---------------- Ball query: one wave per (b,s) ----------------
__global__ __launch_bounds__(256) void ball_kernel(const float* __restrict__ xyz,
                                                   const int* __restrict__ fps_idx,
                                                   int* __restrict__ ball_idx) {
    __shared__ int buf[4][KK];
    const int wave = threadIdx.x >> 6;
    const int lane = threadIdx.x & 63;
    const int gw   = blockIdx.x * 4 + wave;      // gw = b*SS + s
    const int b    = gw / SS;
    const float* xb = xyz + (size_t)b * NN * 3;

    const int   qi = fps_idx[gw];
    const float qx = xb[qi * 3 + 0], qy = xb[qi * 3 + 1], qz = xb[qi * 3 + 2];
    const float qn = __fadd_rn(__fadd_rn(__fmul_rn(qx, qx), __fmul_rn(qy, qy)),
                               __fmul_rn(qz, qz));

    int total = 0;
    for (int base = 0; base < NN && total < KK; base += 64) {
        const int n  = base + lane;
        const float px = xb[n * 3 + 0], py = xb[n * 3 + 1], pz = xb[n * 3 + 2];
        const float pn = __fadd_rn(__fadd_rn(__fmul_rn(px, px), __fmul_rn(py, py)),
                                   __fmul_rn(pz, pz));
        const float dt = __fadd_rn(__fadd_rn(__fmul_rn(qx, px), __fmul_rn(qy, py)),
                                   __fmul_rn(qz, pz));
        // exact ref order: d = (-2*dot) + |q|^2 + |p|^2
        const float d = __fadd_rn(__fadd_rn(__fmul_rn(-2.0f, dt), qn), pn);
        const bool hit = !(d > R2);               // include iff d <= r^2
        const unsigned long long mask = __ballot(hit);
        const int before = __popcll(mask & ((1ull << lane) - 1ull));
        const int pos = total + before;
        if (hit && pos < KK) buf[wave][pos] = n;
        total += (int)__popcll(mask);
    }
    __syncthreads();   // all 4 waves exit loop eventually; makes LDS writes visible
    if (lane < KK) {
        const int v = (lane < total) ? buf[wave][lane] : buf[wave][0];
        ball_idx[gw * KK + lane] = v;
    }
}

// ---------------- Output assembly: one block per (b,s) ----------------
__global__ __launch_bounds__(256) void write_kernel(const float* __restrict__ xyz,
                                                    const float* __restrict__ points,
                                                    const int* __restrict__ fps_idx,
                                                    const int* __restrict__ ball_idx,
                                                    float* __restrict__ out) {
    const int bs = blockIdx.x;                   // 0..B*SS-1
    const int b  = bs / SS;
    __shared__ int   sidx[KK];
    __shared__ float sanchor[DD];
    __shared__ int   sq;
    const int tid = threadIdx.x;

    if (tid < KK) sidx[tid] = ball_idx[bs * KK + tid];
    if (tid == 0) sq = fps_idx[bs];
    __syncthreads();
    const int qi = sq;
    const float* xb = xyz + (size_t)b * NN * 3;
    const float* pb = points + (size_t)b * NN * DD;
    if (tid < DD) sanchor[tid] = pb[qi * DD + tid];
    if (tid < 3)  out[(size_t)bs * 3 + tid] = xb[qi * 3 + tid];
    __syncthreads();

    float* outp = out + (size_t)BB * SS * 3 + (size_t)bs * KK * 131;
    for (int c = tid; c < KK * 131; c += 256) {
        const int k = c / 131;
        const int j = c - k * 131;
        const int idx = sidx[k];
        float v;
        if (j < DD)          v = pb[idx * DD + j];
        else if (j < DD + 3) v = xb[idx * 3 + (j - DD)];
        else                 v = sanchor[j - DD - 3];
        outp[c] = v;
    }
}

extern "C" void kernel_launch(void* const* d_in, const int* in_sizes, int n_in,
                              void* d_out, int out_size, void* d_ws, size_t ws_size,
                              hipStream_t stream) {
    const float* xyz    = (const float*)d_in[0];   // [B,N,3]
    const float* points = (const float*)d_in[1];   // [B,N,D]
    float* out = (float*)d_out;

    int* fps  = (int*)d_ws;                        // [B*S]
    int* ball = fps + BB * SS;                     // [B*S*K]

    fps_kernel<<<BB, 512, 0, stream>>>(xyz, fps);
    ball_kernel<<<(BB * SS) / 4, 256, 0, stream>>>(xyz, fps, ball);
    write_kernel<<<BB * SS, 256, 0, stream>>>(xyz, points, fps, ball, out);
}

// Round 5
// 745.783 us; speedup vs baseline: 3.5136x; 1.0553x over previous
//
#include <hip/hip_runtime.h>

#define BB 8
#define NN 4096
#define DD 64
#define SS 1024
#define KK 32
#define R2 0.04f

typedef float f32x2 __attribute__((ext_vector_type(2)));

// One DPP max stage: wv = max(wv, lanes-shifted wv). old = self -> invalid lanes
// contribute identity. row_shr:1,2,4,8 + row_bcast:15,31 -> lane 63 has wave max.
#define DPP_MAXF(wv, CTRL)                                                             \
    {                                                                                  \
        int _o = __builtin_amdgcn_update_dpp(__float_as_int(wv), __float_as_int(wv),   \
                                             CTRL, 0xf, 0xf, false);                   \
        (wv) = fmaxf((wv), __int_as_float(_o));                                        \
    }

// ---------------- FPS: one block (512 thr) per batch, state in registers ----------------
// Key structural points this revision:
//  * NO global stores inside the step loop (a global store before __syncthreads forces
//    a vmcnt(0) HBM drain on the barrier every step). far-sequence buffered in sfar[].
//  * Per-step u64 result slot red[t] (zeroed once): leaders atomicMax, one barrier,
//    one broadcast ds_read_b64. No parity buffers, no 8-slot compare scan.
//  * Centroid coords via single ds_read_b128 from float4 sxyz[].
// Exactness: distance = ((dx^2+dy^2)+dz^2) per-element RN (pk ops, contract off);
// argmax = max value, smallest index (lex (tid,j) == global index order; u64 key
// (val_bits<<32)|~idx makes unsigned max == first-max).
__global__ __launch_bounds__(512) void fps_kernel(const float* __restrict__ xyz,
                                                  int* __restrict__ fps_idx) {
#pragma clang fp contract(off)
    __shared__ float4 sxyz[NN];                 // 64 KB {x,y,z,pad}
    __shared__ unsigned long long red[SS];      // 8 KB, one slot per step
    __shared__ int sfar[SS];                    // 4 KB

    const int b   = blockIdx.x;
    const int tid = threadIdx.x;
    const float* xb = xyz + (size_t)b * NN * 3;

    for (int i = tid; i < SS; i += 512) red[i] = 0ull;   // slots: zero once

    // ---- init: 96 contiguous bytes per lane (8 points x 3 floats) via 6x float4 ----
    const float4* xb4 = (const float4*)(xb + tid * 24);
    const float4 q0 = xb4[0], q1 = xb4[1], q2 = xb4[2];
    const float4 q3 = xb4[3], q4 = xb4[4], q5 = xb4[5];

    f32x2 px[4], py[4], pz[4], dist[4];
    px[0] = (f32x2){q0.x, q0.w}; py[0] = (f32x2){q0.y, q1.x}; pz[0] = (f32x2){q0.z, q1.y};
    px[1] = (f32x2){q1.z, q2.y}; py[1] = (f32x2){q1.w, q2.z}; pz[1] = (f32x2){q2.x, q2.w};
    px[2] = (f32x2){q3.x, q3.w}; py[2] = (f32x2){q3.y, q4.x}; pz[2] = (f32x2){q3.z, q4.y};
    px[3] = (f32x2){q4.z, q5.y}; py[3] = (f32x2){q4.w, q5.z}; pz[3] = (f32x2){q5.x, q5.w};
#pragma unroll
    for (int jj = 0; jj < 4; ++jj) {
        const int i0 = tid * 8 + 2 * jj;
        sxyz[i0]     = make_float4(px[jj].x, py[jj].x, pz[jj].x, 0.0f);
        sxyz[i0 + 1] = make_float4(px[jj].y, py[jj].y, pz[jj].y, 0.0f);
        dist[jj] = (f32x2){1e10f, 1e10f};
    }
    __syncthreads();

    int far = 0;
    for (int t = 0; t < SS; ++t) {
        if (tid == 0) sfar[t] = far;             // LDS only — no vmcnt drain at barrier
        const float4 c = sxyz[far];              // one ds_read_b128 (broadcast)
        const f32x2 cx2 = (f32x2){c.x, c.x}, cy2 = (f32x2){c.y, c.y}, cz2 = (f32x2){c.z, c.z};

        f32x2 nd[4];
#pragma unroll
        for (int jj = 0; jj < 4; ++jj) {
            // exact ref order: ((dx^2 + dy^2) + dz^2); contract(off) => no FMA
            const f32x2 dx = px[jj] - cx2;
            const f32x2 dy = py[jj] - cy2;
            const f32x2 dz = pz[jj] - cz2;
            const f32x2 d  = (dx * dx + dy * dy) + dz * dz;
            f32x2 m;
            m.x = fminf(dist[jj].x, d.x);        // fmin exact; order-independent
            m.y = fminf(dist[jj].y, d.y);
            dist[jj] = m;
            nd[jj] = m;
        }
        // per-lane max (tree; values non-negative, no NaN)
        const float bestv = fmaxf(fmaxf(fmaxf(nd[0].x, nd[0].y), fmaxf(nd[1].x, nd[1].y)),
                                  fmaxf(fmaxf(nd[2].x, nd[2].y), fmaxf(nd[3].x, nd[3].y)));
        // smallest j achieving it (descending scan => first match wins)
        int localj = 0;
#pragma unroll
        for (int j = 7; j >= 0; --j) {
            const float v = (j & 1) ? nd[j >> 1].y : nd[j >> 1].x;
            if (v == bestv) localj = j;
        }

        // wave max via fused DPP f32 max; recover first-lane index via ballot+ffs
        float wv = bestv;
        DPP_MAXF(wv, 0x111);   // row_shr:1
        DPP_MAXF(wv, 0x112);   // row_shr:2
        DPP_MAXF(wv, 0x114);   // row_shr:4
        DPP_MAXF(wv, 0x118);   // row_shr:8
        DPP_MAXF(wv, 0x142);   // row_bcast:15
        DPP_MAXF(wv, 0x143);   // row_bcast:31
        const float maxw = __int_as_float(__builtin_amdgcn_readlane(__float_as_int(wv), 63));

        const unsigned long long hits = __ballot(bestv == maxw);
        const int L = __ffsll(hits) - 1;         // smallest lane == smallest tid == smallest i
        const int candv = tid * 8 + localj;      // global point index
        const int cand  = __builtin_amdgcn_readlane(candv, L);

        // leaders race into the per-step slot; u64 max == (max val, then min index)
        if ((tid & 63) == 0) {
            const unsigned long long p =
                ((unsigned long long)__float_as_uint(maxw) << 32) | (unsigned)(~cand);
            atomicMax(&red[t], p);
        }
        __syncthreads();                         // the only barrier in the step
        far = (int)(~(unsigned)red[t]);          // broadcast ds_read_b64
    }
    __syncthreads();
    for (int i = tid; i < SS; i += 512) fps_idx[b * SS + i] = sfar[i];
}

// ---------------- Ball query: one wave per (b,s) ----------------
__global__ __launch_bounds__(256) void ball_kernel(const float* __restrict__ xyz,
                                                   const int* __restrict__ fps_idx,
                                                   int* __restrict__ ball_idx) {
    __shared__ int buf[4][KK];
    const int wave = threadIdx.x >> 6;
    const int lane = threadIdx.x & 63;
    const int gw   = blockIdx.x * 4 + wave;      // gw = b*SS + s
    const int b    = gw / SS;
    const float* xb = xyz + (size_t)b * NN * 3;

    const int   qi = fps_idx[gw];
    const float qx = xb[qi * 3 + 0], qy = xb[qi * 3 + 1], qz = xb[qi * 3 + 2];
    const float qn = __fadd_rn(__fadd_rn(__fmul_rn(qx, qx), __fmul_rn(qy, qy)),
                               __fmul_rn(qz, qz));

    int total = 0;
    for (int base = 0; base < NN && total < KK; base += 64) {
        const int n  = base + lane;
        const float px = xb[n * 3 + 0], py = xb[n * 3 + 1], pz = xb[n * 3 + 2];
        const float pn = __fadd_rn(__fadd_rn(__fmul_rn(px, px), __fmul_rn(py, py)),
                                   __fmul_rn(pz, pz));
        const float dt = __fadd_rn(__fadd_rn(__fmul_rn(qx, px), __fmul_rn(qy, py)),
                                   __fmul_rn(qz, pz));
        // exact ref order: d = (-2*dot) + |q|^2 + |p|^2
        const float d = __fadd_rn(__fadd_rn(__fmul_rn(-2.0f, dt), qn), pn);
        const bool hit = !(d > R2);               // include iff d <= r^2
        const unsigned long long mask = __ballot(hit);
        const int before = __popcll(mask & ((1ull << lane) - 1ull));
        const int pos = total + before;
        if (hit && pos < KK) buf[wave][pos] = n;
        total += (int)__popcll(mask);
    }
    __syncthreads();   // all 4 waves exit loop eventually; makes LDS writes visible
    if (lane < KK) {
        const int v = (lane < total) ? buf[wave][lane] : buf[wave][0];
        ball_idx[gw * KK + lane] = v;
    }
}

// ---------------- Output assembly: one block per (b,s) ----------------
__global__ __launch_bounds__(256) void write_kernel(const float* __restrict__ xyz,
                                                    const float* __restrict__ points,
                                                    const int* __restrict__ fps_idx,
                                                    const int* __restrict__ ball_idx,
                                                    float* __restrict__ out) {
    const int bs = blockIdx.x;                   // 0..B*SS-1
    const int b  = bs / SS;
    __shared__ int   sidx[KK];
    __shared__ float sanchor[DD];
    __shared__ int   sq;
    const int tid = threadIdx.x;

    if (tid < KK) sidx[tid] = ball_idx[bs * KK + tid];
    if (tid == 0) sq = fps_idx[bs];
    __syncthreads();
    const int qi = sq;
    const float* xb = xyz + (size_t)b * NN * 3;
    const float* pb = points + (size_t)b * NN * DD;
    if (tid < DD) sanchor[tid] = pb[qi * DD + tid];
    if (tid < 3)  out[(size_t)bs * 3 + tid] = xb[qi * 3 + tid];
    __syncthreads();

    float* outp = out + (size_t)BB * SS * 3 + (size_t)bs * KK * 131;
    for (int c = tid; c < KK * 131; c += 256) {
        const int k = c / 131;
        const int j = c - k * 131;
        const int idx = sidx[k];
        float v;
        if (j < DD)          v = pb[idx * DD + j];
        else if (j < DD + 3) v = xb[idx * 3 + (j - DD)];
        else                 v = sanchor[j - DD - 3];
        outp[c] = v;
    }
}

extern "C" void kernel_launch(void* const* d_in, const int* in_sizes, int n_in,
                              void* d_out, int out_size, void* d_ws, size_t ws_size,
                              hipStream_t stream) {
    const float* xyz    = (const float*)d_in[0];   // [B,N,3]
    const float* points = (const float*)d_in[1];   // [B,N,D]
    float* out = (float*)d_out;

    int* fps  = (int*)d_ws;                        // [B*S]
    int* ball = fps + BB * SS;                     // [B*S*K]

    fps_kernel<<<BB, 512, 0, stream>>>(xyz, fps);
    ball_kernel<<<(BB * SS) / 4, 256, 0, stream>>>(xyz, fps, ball);
    write_kernel<<<BB * SS, 256, 0, stream>>>(xyz, points, fps, ball, out);
}